// Round 27
// baseline (41.843 us; speedup 1.0000x reference)
//
#include <hip/hip_runtime.h>

// ConvDatapath: bit-serial crossbar conv with per-chunk ADC quantization.
// R26 state: k_q v7 14.9 + k_d 18.6 = 33.5. k_q is GATHER-bound (~190
// distinct cache lines per row; ~157MB line traffic). This round:
// k_q v8: block = one 16-row tile. Phase A: transposed coalesced im2col
//         load (thread's row fixed, loop k) -> raw floats in LDS [k][17]
//         (~14MB total traffic, 10x less). Phase B: 16-lane quant36
//         (R21/R22-proven bit-exact) from LDS -> 656-stride row buffer.
//         Phase C: R23-proven fully-coalesced fragment store.
//         W-rows: v7 path verbatim (blocks 392..423).
// k_d   : R11/R26 verbatim (18.6us; best across 10 structural variants).
// Integer path bit-exact vs reference. Nx=6272, Ny=128, K=576 (5x116->128).

#define NXROW 6272
#define KDIM  576
#define NPB   116
#define SSTR  656    // row stride: 41*16, b128-aligned

typedef int i32x4 __attribute__((ext_vector_type(4)));

__device__ __forceinline__ i32x4 slice2b(i32x4 v, int sh) {
    i32x4 r;
    r[0] = (int)(((unsigned)v[0] >> sh) & 0x03030303u);
    r[1] = (int)(((unsigned)v[1] >> sh) & 0x03030303u);
    r[2] = (int)(((unsigned)v[2] >> sh) & 0x03030303u);
    r[3] = (int)(((unsigned)v[3] >> sh) & 0x03030303u);
    return r;
}

// 16-lane-group row quantizer (R21/R22-proven sequence): lane i16 holds
// k = 36*i16 + j (k-ascending). 4-step butterfly (exact); IEEE div; writes
// 9 dword-aligned b32 at col = k + 12*(k/116); each lane zeroes 1 pad dword.
__device__ __forceinline__ void quant36(const float (&v)[36], unsigned char* rowp,
                                        int i16, float* scp, float* ofp, float* smp)
{
    {   // 16 pad dwords per row: chunks 0..3 cols 116..127, chunk 4 cols 624..639
        int col = i16 < 12 ? (i16 / 3) * 128 + 116 + (i16 % 3) * 4
                           : 624 + (i16 - 12) * 4;
        *(unsigned int*)(rowp + col) = 0u;
    }
    float mn = v[0], mx = v[0], sm = 0.f;
#pragma unroll
    for (int m = 0; m < 36; m++) { mn = fminf(mn, v[m]); mx = fmaxf(mx, v[m]); sm += v[m]; }
#pragma unroll
    for (int off = 1; off < 16; off <<= 1) {
        mn = fminf(mn, __shfl_xor(mn, off));
        mx = fmaxf(mx, __shfl_xor(mx, off));
        sm += __shfl_xor(sm, off);
    }
    float step = (mx - mn) / 255.0f;      // IEEE — bit-exact vs reference
    if (i16 == 0) { *scp = step; *ofp = mn; *smp = sm; }
    int k0 = i16 * 36;
#pragma unroll
    for (int d = 0; d < 9; d++) {
        unsigned int dw = 0;
#pragma unroll
        for (int mb = 0; mb < 4; mb++) {
            int q = (int)rintf((v[d * 4 + mb] - mn) / step);   // IEEE div
            q = q < 0 ? 0 : (q > 255 ? 255 : q);
            dw |= (unsigned)q << (8 * mb);
        }
        int kd = k0 + d * 4;
        int ch = kd / NPB;
        *(unsigned int*)(rowp + kd + 12 * ch) = dw;
    }
}

// ---------------- kernel 1: quantization ----------------
// blk < 392: x-tile blk (16 rows). blk 392..423: w rows (blk-392)*4 + wv.
__global__ __launch_bounds__(256) void k_q(
    const float* __restrict__ x, const float* __restrict__ w,
    unsigned char* __restrict__ Xq, unsigned char* __restrict__ Wq,
    float* __restrict__ xsc, float* __restrict__ xof, float* __restrict__ xsm,
    float* __restrict__ wsc, float* __restrict__ wof, float* __restrict__ wsm)
{
    __shared__ float rawf[576 * 17];                        // [k][row], stride 17
    __shared__ __align__(16) unsigned char qrow[16 * SSTR]; // quantized rows

    int tid = threadIdx.x, wv = tid >> 6, lane = tid & 63;
    int blk = blockIdx.x;

    if (blk < 392) {
        // ---- phase A: transposed coalesced im2col load -> rawf
        int row = tid & 15;               // fixed per thread
        int R = blk * 16 + row;           // global x-row
        int b = R >= 3136 ? 1 : 0;
        int pos = R - b * 3136;
        int hg = pos / 56, wg = pos - hg * 56;
        const float* xb = x + (size_t)(b * 64) * 3136;
        int kbase = tid >> 4;             // 0..15
#pragma unroll
        for (int it = 0; it < 36; it++) {
            int k = kbase + it * 16;
            int cin = k / 9;              // magic-mul
            int off = k - cin * 9;        // [cin][kh][kw] (ref im2col order)
            int kh = off / 3, kw = off - kh * 3;
            int hr = hg - 1 + kh, wc = wg - 1 + kw;
            bool ok = ((unsigned)hr < 56u) && ((unsigned)wc < 56u);
            rawf[k * 17 + row] = ok ? xb[cin * 3136 + hr * 56 + wc] : 0.f;
        }
        __syncthreads();

        // ---- phase B: 16-lane quant36 from LDS; wave wv -> rows wv*4..+3
        int i16 = lane & 15;
        int r = wv * 4 + (lane >> 4);     // row 0..15
        float v[36];
#pragma unroll
        for (int j = 0; j < 36; j++)
            v[j] = rawf[(i16 * 36 + j) * 17 + r];
        quant36(v, qrow + r * SSTR, i16,
                xsc + blk * 16 + r, xof + blk * 16 + r, xsm + blk * 16 + r);
        __syncthreads();

        // ---- phase C: coalesced fragment store (R23-proven mapping)
        unsigned char* dst = Xq + (size_t)blk * 10240;
        for (int s = tid; s < 640; s += 256) {
            int rl = s & 15;
            int u = (s >> 7) * 8 + ((s >> 6) & 1) * 4 + ((s >> 4) & 3);
            *(i32x4*)(dst + (size_t)s * 16) = *(const i32x4*)(&qrow[rl * SSTR + u * 16]);
        }
    } else {
        // ---- w path (v7 verbatim): one row per wave
        int row = (blk - 392) * 4 + wv;   // 0..127
        unsigned char* myrow = qrow + wv * SSTR;
        if (lane < 16) {
            int col = lane < 12 ? (lane / 3) * 128 + 116 + (lane % 3) * 4
                                : 624 + (lane - 12) * 4;
            *(unsigned int*)(myrow + col) = 0u;
        }
        const float* wr = w + (size_t)row * KDIM;
        float v[9];
#pragma unroll
        for (int r = 0; r < 9; r++) v[r] = wr[r * 64 + lane];
        float mn = v[0], mx = v[0], s = 0.f;
#pragma unroll
        for (int r = 0; r < 9; r++) { mn = fminf(mn, v[r]); mx = fmaxf(mx, v[r]); s += v[r]; }
#pragma unroll
        for (int off2 = 1; off2 < 64; off2 <<= 1) {
            mn = fminf(mn, __shfl_xor(mn, off2));
            mx = fmaxf(mx, __shfl_xor(mx, off2));
            s += __shfl_xor(s, off2);
        }
        float step = (mx - mn) / 255.0f;
        if (lane == 0) { wsc[row] = step; wof[row] = mn; wsm[row] = s; }
#pragma unroll
        for (int r = 0; r < 9; r++) {
            int q = (int)rintf((v[r] - mn) / step);
            q = q < 0 ? 0 : (q > 255 ? 255 : q);
            int k = r * 64 + lane;
            int ch = k / NPB;
            myrow[k + 12 * ch] = (unsigned char)q;
        }
        __syncthreads();
        if (lane < 40) {
            int u = lane;
            i32x4 seg = *(const i32x4*)(myrow + u * 16);
            int dst16 = (u >> 3) * 128 + ((u >> 2) & 1) * 64 + (u & 3) * 16 + (row & 15);
            *(i32x4*)(Wq + (size_t)(row >> 4) * 10240 + (size_t)dst16 * 16) = seg;
        }
    }
}

// ---------------- kernel 2: crossbar MFMA + ADC + dequant (R11 verbatim) ----
__device__ __forceinline__ void chunk_ws(const unsigned char* xt, const unsigned char* wt,
                                         int ch, int lane, i32x4 (&acc4)[4])
{
    const i32x4 zero = {0, 0, 0, 0};
    i32x4 x0 = *(const i32x4*)(xt + ch * 2048 + lane * 16);
    i32x4 x1 = *(const i32x4*)(xt + ch * 2048 + 1024 + lane * 16);
    i32x4 w0 = *(const i32x4*)(wt + ch * 2048 + lane * 16);
    i32x4 w1 = *(const i32x4*)(wt + ch * 2048 + 1024 + lane * 16);
    i32x4 ws0[4], ws1[4];
#pragma unroll
    for (int ws = 0; ws < 4; ws++) {
        ws0[ws] = slice2b(w0, 6 - 2 * ws);
        ws1[ws] = slice2b(w1, 6 - 2 * ws);
    }
#pragma unroll
    for (int is = 0; is < 4; is++) {
        int ish = 6 - 2 * is;
        i32x4 a0 = slice2b(x0, ish), a1 = slice2b(x1, ish);
#pragma unroll
        for (int ws = 0; ws < 4; ws++) {
            i32x4 d = __builtin_amdgcn_mfma_i32_16x16x64_i8(ws0[ws], a0, zero, 0, 0, 0);
            d = __builtin_amdgcn_mfma_i32_16x16x64_i8(ws1[ws], a1, d, 0, 0, 0);
            int sh = ish + 6 - 2 * ws;
#pragma unroll
            for (int r = 0; r < 4; r++) {
                int z = d[r];
                z = z > 1024 ? 1024 : z;                 // ADC clip (z >= 0)
                int t = (z >> 2) & 1;
                int r4 = (z + 1 + t) & ~3;               // round-half-even, mult of 4
                acc4[ws][r] += r4 << sh;                 // 2^(ish+wsh)
            }
        }
    }
}

__global__ __launch_bounds__(256) void k_d(
    const unsigned char* __restrict__ Xq, const unsigned char* __restrict__ Wq,
    const float* __restrict__ xscg, const float* __restrict__ xofg,
    const float* __restrict__ xsmg,
    const float* __restrict__ wscg, const float* __restrict__ wofg,
    const float* __restrict__ wsmg, float* __restrict__ out)
{
    __shared__ __align__(16) int pacc[2][64][4];

    int tid = threadIdx.x, wv = tid >> 6, lane = tid & 63;
    int g = lane >> 4, i16 = lane & 15;
    int blk = blockIdx.x;                 // 0..1567
    int ct = blk & 7, rp = blk >> 3;      // rp 0..195
    int tl = wv & 1, khalf = wv >> 1;
    int rtile = rp * 2 + tl;              // 0..391
    const unsigned char* xt = Xq + (size_t)rtile * 10240;
    const unsigned char* wt = Wq + (size_t)ct * 10240;

    i32x4 acc4[4] = {{0,0,0,0},{0,0,0,0},{0,0,0,0},{0,0,0,0}};
    if (khalf == 0) {
        chunk_ws(xt, wt, 0, lane, acc4);
        chunk_ws(xt, wt, 1, lane, acc4);
        chunk_ws(xt, wt, 2, lane, acc4);
    } else {
        chunk_ws(xt, wt, 3, lane, acc4);
        chunk_ws(xt, wt, 4, lane, acc4);
    }
    i32x4 acc;
#pragma unroll
    for (int r = 0; r < 4; r++)
        acc[r] = (acc4[0][r] + acc4[1][r]) + (acc4[2][r] + acc4[3][r]);  // exact

    if (khalf == 0) *(i32x4*)&pacc[tl][lane][0] = acc;
    __syncthreads();

    if (khalf == 1) {
        i32x4 p = *(const i32x4*)&pacc[tl][lane][0];
#pragma unroll
        for (int r = 0; r < 4; r++) acc[r] += p[r];      // chunk-sum, exact

        // epilogue: D[row = w-row (g*4+r), col = x-row (i16)]; 64B coalesced
        int b = rtile >= 196 ? 1 : 0;
        int xrow = rtile * 16 + i16;
        float xs_ = xscg[xrow], xo = xofg[xrow], xsv = xsmg[xrow];
        int hw = (rtile - 196 * b) * 16 + i16;
#pragma unroll
        for (int r = 0; r < 4; r++) {
            int wrow = ct * 16 + g * 4 + r;
            float tt = ((float)acc[r] * xs_) * wscg[wrow];
            float res = ((tt + xo * wsmg[wrow]) + wofg[wrow] * xsv)
                      - (xo * wofg[wrow]) * 576.0f;
            out[(size_t)(b * 128 + wrow) * 3136 + hw] = res;
        }
    }
}

extern "C" void kernel_launch(void* const* d_in, const int* in_sizes, int n_in,
                              void* d_out, int out_size, void* d_ws, size_t ws_size,
                              hipStream_t stream) {
    const float* x = (const float*)d_in[0];   // [2][64][56][56]
    const float* w = (const float*)d_in[1];   // [128][64][3][3]
    float* out = (float*)d_out;               // [2][128][56][56]

    unsigned char* Xq = (unsigned char*)d_ws;          // 392*10,240 = 4,014,080 B
    unsigned char* Wq = Xq + (size_t)392 * 10240;      // 8*10,240   = 81,920 B
    float* xsc = (float*)(Wq + 8 * 10240);
    float* xof = xsc + NXROW;
    float* xsm = xof + NXROW;
    float* wsc = xsm + NXROW;
    float* wof = wsc + 128;
    float* wsm = wof + 128;

    hipLaunchKernelGGL(k_q, dim3(424), dim3(256), 0, stream,
                       x, w, Xq, Wq, xsc, xof, xsm, wsc, wof, wsm);
    hipLaunchKernelGGL(k_d, dim3(1568), dim3(256), 0, stream,
                       Xq, Wq, xsc, xof, xsm, wsc, wof, wsm, out);
}

// Round 28
// 35.679 us; speedup vs baseline: 1.1728x; 1.1728x over previous
//
#include <hip/hip_runtime.h>

// ConvDatapath: bit-serial crossbar conv with per-chunk ADC quantization.
// R22 fusion retried WITHOUT quant redundancy (R22's block=(rtile,cq) did
// 4x redundant x-quant = +18us; rule: row-quant ~1us/1000 rows).
// k_wq  : 32 blocks, one w-row per wave (R22 verbatim) -> fragment Wq.
// k_main: 392 blocks x 512 thr, block = rtile. Phase Q: 8 waves x 2 rows —
//         each tile row quantized ONCE (v7 64-lane quant core) into LDS
//         656-stride rows. Barrier. Phase D: wave = ct (0..7), full 5-chunk
//         depth (R22 chunk_ws verbatim; X-frags from LDS rows, W-frags from
//         global Wq), per-wave epilogue (no pacc). Xq roundtrip deleted.
// Integer path bit-exact vs reference. Nx=6272, Ny=128, K=576 (5x116->128).

#define NXROW 6272
#define KDIM  576
#define NPB   116
#define SSTR  656    // LDS row stride: 41*16, b128-aligned; 164 dw % 32 = 4

typedef int i32x4 __attribute__((ext_vector_type(4)));

__device__ __forceinline__ i32x4 slice2b(i32x4 v, int sh) {
    i32x4 r;
    r[0] = (int)(((unsigned)v[0] >> sh) & 0x03030303u);
    r[1] = (int)(((unsigned)v[1] >> sh) & 0x03030303u);
    r[2] = (int)(((unsigned)v[2] >> sh) & 0x03030303u);
    r[3] = (int)(((unsigned)v[3] >> sh) & 0x03030303u);
    return r;
}

// v7 64-lane row-quant core (R21/R26-proven): lane holds k = r*64+lane.
// Exact butterfly stats; IEEE div; bytes to row at col = k + 12*(k/116);
// pads zeroed by lane<16 first. Scales to LDS (or global) floats.
__device__ __forceinline__ void rowquant64(const float (&v)[9], unsigned char* myrow,
                                           int lane, float* scp, float* ofp, float* smp)
{
    if (lane < 16) {
        int col = lane < 12 ? (lane / 3) * 128 + 116 + (lane % 3) * 4
                            : 624 + (lane - 12) * 4;
        *(unsigned int*)(myrow + col) = 0u;
    }
    float mn = v[0], mx = v[0], s = 0.f;
#pragma unroll
    for (int r = 0; r < 9; r++) { mn = fminf(mn, v[r]); mx = fmaxf(mx, v[r]); s += v[r]; }
#pragma unroll
    for (int off2 = 1; off2 < 64; off2 <<= 1) {
        mn = fminf(mn, __shfl_xor(mn, off2));
        mx = fmaxf(mx, __shfl_xor(mx, off2));
        s += __shfl_xor(s, off2);
    }
    float step = (mx - mn) / 255.0f;      // IEEE — bit-exact vs reference
    if (lane == 0) { *scp = step; *ofp = mn; *smp = s; }
#pragma unroll
    for (int r = 0; r < 9; r++) {
        int q = (int)rintf((v[r] - mn) / step);   // IEEE div — bit-exact
        q = q < 0 ? 0 : (q > 255 ? 255 : q);
        int k = r * 64 + lane;
        int ch = k / NPB;
        myrow[k + 12 * ch] = (unsigned char)q;
    }
}

// ---------------- kernel 1: w quantization (one row per wave) ----------------
__global__ __launch_bounds__(256) void k_wq(
    const float* __restrict__ w, unsigned char* __restrict__ Wq,
    float* __restrict__ wsc, float* __restrict__ wof, float* __restrict__ wsm)
{
    __shared__ __align__(16) unsigned char scr[4][SSTR];
    int tid = threadIdx.x, wv = tid >> 6, lane = tid & 63;
    int row = blockIdx.x * 4 + wv;        // 0..127
    unsigned char* myrow = scr[wv];

    const float* wr = w + (size_t)row * KDIM;
    float v[9];
#pragma unroll
    for (int r = 0; r < 9; r++) v[r] = wr[r * 64 + lane];   // coalesced

    rowquant64(v, myrow, lane, wsc + row, wof + row, wsm + row);
    __syncthreads();

    // scatter to fragment layout (R21/R22-proven)
    if (lane < 40) {
        int u = lane;
        i32x4 seg = *(const i32x4*)(myrow + u * 16);
        int dst16 = (u >> 3) * 128 + ((u >> 2) & 1) * 64 + (u & 3) * 16 + (row & 15);
        *(i32x4*)(Wq + (size_t)(row >> 4) * 10240 + (size_t)dst16 * 16) = seg;
    }
}

// ---------------- kernel 2: fused x-quant + crossbar MFMA + ADC + dequant ----
// one chunk into 4 per-ws accumulators (R22 verbatim: X from LDS rows)
__device__ __forceinline__ void chunk_ws(const unsigned char* xp, const unsigned char* wt,
                                         int ch, int lane, i32x4 (&acc4)[4])
{
    const i32x4 zero = {0, 0, 0, 0};
    i32x4 x0 = *(const i32x4*)(xp + ch * 128);
    i32x4 x1 = *(const i32x4*)(xp + ch * 128 + 64);
    i32x4 w0 = *(const i32x4*)(wt + ch * 2048 + lane * 16);
    i32x4 w1 = *(const i32x4*)(wt + ch * 2048 + 1024 + lane * 16);
    i32x4 ws0[4], ws1[4];
#pragma unroll
    for (int ws = 0; ws < 4; ws++) {
        ws0[ws] = slice2b(w0, 6 - 2 * ws);
        ws1[ws] = slice2b(w1, 6 - 2 * ws);
    }
#pragma unroll
    for (int is = 0; is < 4; is++) {
        int ish = 6 - 2 * is;
        i32x4 a0 = slice2b(x0, ish), a1 = slice2b(x1, ish);
#pragma unroll
        for (int ws = 0; ws < 4; ws++) {
            i32x4 d = __builtin_amdgcn_mfma_i32_16x16x64_i8(ws0[ws], a0, zero, 0, 0, 0);
            d = __builtin_amdgcn_mfma_i32_16x16x64_i8(ws1[ws], a1, d, 0, 0, 0);
            int sh = ish + 6 - 2 * ws;
#pragma unroll
            for (int r = 0; r < 4; r++) {
                int z = d[r];
                z = z > 1024 ? 1024 : z;                 // ADC clip (z >= 0)
                int t = (z >> 2) & 1;
                int r4 = (z + 1 + t) & ~3;               // round-half-even, mult of 4
                acc4[ws][r] += r4 << sh;                 // 2^(ish+wsh)
            }
        }
    }
}

__global__ __launch_bounds__(512) void k_main(
    const float* __restrict__ x, const unsigned char* __restrict__ Wq,
    const float* __restrict__ wscg, const float* __restrict__ wofg,
    const float* __restrict__ wsmg, float* __restrict__ out)
{
    __shared__ __align__(16) unsigned char scrX[16 * SSTR];   // 10,496 B
    __shared__ float xscl[16], xofl[16], xsml[16];

    int tid = threadIdx.x, wv = tid >> 6, lane = tid & 63;
    int g = lane >> 4, i16 = lane & 15;
    int rtile = blockIdx.x;               // 0..391
    int b = rtile >= 196 ? 1 : 0;
    int pos0 = (rtile - 196 * b) * 16;
    const float* xb = x + (size_t)(b * 64) * 3136;

    // ---- phase Q: 8 waves x 2 rows — each row quantized exactly once
#pragma unroll
    for (int q = 0; q < 2; q++) {
        int i = wv * 2 + q;               // tile-local row 0..15
        int pos = pos0 + i;
        int hg = pos / 56, wg = pos - hg * 56;
        float v[9];
#pragma unroll
        for (int r = 0; r < 9; r++) {
            int k = r * 64 + lane;
            int cin = k / 9;              // magic-mul
            int off = k - cin * 9;        // [cin][kh][kw] (ref im2col order)
            int kh = off / 3;
            int kw = off - kh * 3;
            int hr = hg - 1 + kh, wc = wg - 1 + kw;
            bool ok = ((unsigned)hr < 56u) && ((unsigned)wc < 56u);
            v[r] = ok ? xb[cin * 3136 + hr * 56 + wc] : 0.f;
        }
        rowquant64(v, scrX + i * SSTR, lane, xscl + i, xofl + i, xsml + i);
    }
    __syncthreads();

    // ---- phase D: wave = ct (0..7), full 5-chunk depth, no pacc
    int ct = wv;
    const unsigned char* xp = scrX + i16 * SSTR + g * 16;   // R8/R22-proven
    const unsigned char* wt = Wq + (size_t)ct * 10240;

    i32x4 acc4[4] = {{0,0,0,0},{0,0,0,0},{0,0,0,0},{0,0,0,0}};
    chunk_ws(xp, wt, 0, lane, acc4);
    chunk_ws(xp, wt, 1, lane, acc4);
    chunk_ws(xp, wt, 2, lane, acc4);
    chunk_ws(xp, wt, 3, lane, acc4);
    chunk_ws(xp, wt, 4, lane, acc4);

    i32x4 acc;
#pragma unroll
    for (int r = 0; r < 4; r++)
        acc[r] = (acc4[0][r] + acc4[1][r]) + (acc4[2][r] + acc4[3][r]);  // exact

    // epilogue: D[row = w-row (g*4+r), col = x-row (i16)]; 64B coalesced
    float xs_ = xscl[i16], xo = xofl[i16], xsv = xsml[i16];
    int hw = pos0 + i16;
#pragma unroll
    for (int r = 0; r < 4; r++) {
        int wrow = ct * 16 + g * 4 + r;
        float tt = ((float)acc[r] * xs_) * wscg[wrow];
        float res = ((tt + xo * wsmg[wrow]) + wofg[wrow] * xsv)
                  - (xo * wofg[wrow]) * 576.0f;
        out[(size_t)(b * 128 + wrow) * 3136 + hw] = res;
    }
}

extern "C" void kernel_launch(void* const* d_in, const int* in_sizes, int n_in,
                              void* d_out, int out_size, void* d_ws, size_t ws_size,
                              hipStream_t stream) {
    const float* x = (const float*)d_in[0];   // [2][64][56][56]
    const float* w = (const float*)d_in[1];   // [128][64][3][3]
    float* out = (float*)d_out;               // [2][128][56][56]

    unsigned char* Wq = (unsigned char*)d_ws; // 8*10,240 = 81,920 B
    float* wsc = (float*)(Wq + 8 * 10240);
    float* wof = wsc + 128;
    float* wsm = wof + 128;

    hipLaunchKernelGGL(k_wq, dim3(32), dim3(256), 0, stream,
                       w, Wq, wsc, wof, wsm);
    hipLaunchKernelGGL(k_main, dim3(392), dim3(512), 0, stream,
                       x, Wq, wsc, wof, wsm, out);
}

// Round 29
// 33.289 us; speedup vs baseline: 1.2569x; 1.0718x over previous
//
#include <hip/hip_runtime.h>

// ConvDatapath: bit-serial crossbar conv with per-chunk ADC quantization.
// FINAL (R26 restore — best measured: 33.5us = k_q v7 14.9 + k_d 18.6).
// k_q v7: one row per wave (6400 waves); per-wave LDS row bounce; block-
//         cooperative fragment store (4 rows/block share one tile; 4 tids
//         write one contiguous 64B line).
// k_d   : R11 structure (best across 10+ variants): 1568 blocks, wave =
//         (tile, khalf); 4 per-ws accumulator chains; pacc combine;
//         swapped-operand MFMA (C/D col = x position) -> coalesced stores.
// Integer path bit-exact vs reference (absmax 0.75 across all rounds).
// Nx = 6272, Ny = 128, K = 576 (5 chunks of 116, padded to 128).

#define NXROW 6272
#define KDIM  576
#define NPB   116
#define SSTR  656    // LDS row stride: 41*16, b128-aligned; 164 dw % 32 = 4

typedef int i32x4 __attribute__((ext_vector_type(4)));

__device__ __forceinline__ i32x4 slice2b(i32x4 v, int sh) {
    i32x4 r;
    r[0] = (int)(((unsigned)v[0] >> sh) & 0x03030303u);
    r[1] = (int)(((unsigned)v[1] >> sh) & 0x03030303u);
    r[2] = (int)(((unsigned)v[2] >> sh) & 0x03030303u);
    r[3] = (int)(((unsigned)v[3] >> sh) & 0x03030303u);
    return r;
}

// ---------------- kernel 1: quantization, one row per wave ----------------
// wave W < 6272: im2col x-row W; else w-row W-6272. Rows 4b..4b+3 share one
// 16-row tile (never cross a 16-boundary) and one side (6272 % 4 == 0).
__global__ __launch_bounds__(256) void k_q(
    const float* __restrict__ x, const float* __restrict__ w,
    unsigned char* __restrict__ Xq, unsigned char* __restrict__ Wq,
    float* __restrict__ xsc, float* __restrict__ xof, float* __restrict__ xsm,
    float* __restrict__ wsc, float* __restrict__ wof, float* __restrict__ wsm)
{
    __shared__ __align__(16) unsigned char scr[4][SSTR];  // per-wave row

    int tid = threadIdx.x, wv = tid >> 6, lane = tid & 63;
    int W = blockIdx.x * 4 + wv;          // 0..6399, wave-uniform
    unsigned char* myrow = scr[wv];

    // zero this row's K-pad dwords (cols ch*128+116..127, 624..639)
    if (lane < 16) {
        int col = lane < 12 ? (lane / 3) * 128 + 116 + (lane % 3) * 4
                            : 624 + (lane - 12) * 4;
        *(unsigned int*)(myrow + col) = 0u;
    }

    float v[9];
    float *sc, *of, *sm;
    int sidx;

    if (W < NXROW) {
        int b = W >= 3136 ? 1 : 0;
        int pos = W - b * 3136;
        int hg = pos / 56, wg = pos - hg * 56;
        const float* xb = x + (size_t)(b * 64) * 3136;
#pragma unroll
        for (int r = 0; r < 9; r++) {
            int k = r * 64 + lane;
            int cin = k / 9;              // magic-mul
            int off = k - cin * 9;        // [cin][kh][kw] (ref im2col order)
            int kh = off / 3;
            int kw = off - kh * 3;
            int hr = hg - 1 + kh, wc = wg - 1 + kw;
            bool ok = ((unsigned)hr < 56u) && ((unsigned)wc < 56u);
            v[r] = ok ? xb[cin * 3136 + hr * 56 + wc] : 0.f;
        }
        sc = xsc; of = xof; sm = xsm; sidx = W;
    } else {
        int row = W - NXROW;              // 0..127
        const float* wr = w + (size_t)row * KDIM;
#pragma unroll
        for (int r = 0; r < 9; r++) v[r] = wr[r * 64 + lane];
        sc = wsc; of = wof; sm = wsm; sidx = row;
    }

    // stats: exact min/max; butterfly sum (R20/R21-proven, absmax 0.75)
    float mn = v[0], mx = v[0], s = 0.f;
#pragma unroll
    for (int r = 0; r < 9; r++) { mn = fminf(mn, v[r]); mx = fmaxf(mx, v[r]); s += v[r]; }
#pragma unroll
    for (int off2 = 1; off2 < 64; off2 <<= 1) {
        mn = fminf(mn, __shfl_xor(mn, off2));
        mx = fmaxf(mx, __shfl_xor(mx, off2));
        s += __shfl_xor(s, off2);
    }
    float step = (mx - mn) / 255.0f;      // IEEE — bit-exact vs reference
    if (lane == 0) { sc[sidx] = step; of[sidx] = mn; sm[sidx] = s; }

    // quantize into this wave's LDS row: col = k + 12*(k/116) = ch*128 + k%116
#pragma unroll
    for (int r = 0; r < 9; r++) {
        int q = (int)rintf((v[r] - mn) / step);   // IEEE div — bit-exact
        q = q < 0 ? 0 : (q > 255 ? 255 : q);
        int k = r * 64 + lane;
        int ch = k / NPB;
        myrow[k + 12 * ch] = (unsigned char)q;
    }
    __syncthreads();   // uniform: orders LDS writes before cooperative store

    // block-cooperative fragment store: 160 segments (4 rows x 40 u).
    // dst16 = (u>>3)*128 + ((u>>2)&1)*64 + (u&3)*16 + rl; 4 consecutive tids
    // (same u, dr=0..3) write 4 consecutive 16B runs = one 64B line.
    if (tid < 160) {
        int u = tid >> 2, dr = tid & 3;
        int row0 = blockIdx.x * 4;        // block-uniform
        bool isx = row0 < NXROW;
        int lrow = (isx ? row0 : row0 - NXROW) + dr;
        int tile = lrow >> 4, rl = lrow & 15;
        unsigned char* dstbase = (isx ? Xq : Wq) + (size_t)tile * 10240;
        i32x4 seg = *(const i32x4*)(scr[dr] + u * 16);
        int dst16 = (u >> 3) * 128 + ((u >> 2) & 1) * 64 + (u & 3) * 16 + rl;
        *(i32x4*)(dstbase + (size_t)dst16 * 16) = seg;
    }
}

// ---------------- kernel 2: crossbar MFMA + ADC + dequant (R11 verbatim) ----
// one chunk, accumulating into 4 per-ws accumulators (4 indep chains)
__device__ __forceinline__ void chunk_ws(const unsigned char* xt, const unsigned char* wt,
                                         int ch, int lane, i32x4 (&acc4)[4])
{
    const i32x4 zero = {0, 0, 0, 0};
    i32x4 x0 = *(const i32x4*)(xt + ch * 2048 + lane * 16);
    i32x4 x1 = *(const i32x4*)(xt + ch * 2048 + 1024 + lane * 16);
    i32x4 w0 = *(const i32x4*)(wt + ch * 2048 + lane * 16);
    i32x4 w1 = *(const i32x4*)(wt + ch * 2048 + 1024 + lane * 16);
    i32x4 ws0[4], ws1[4];
#pragma unroll
    for (int ws = 0; ws < 4; ws++) {
        ws0[ws] = slice2b(w0, 6 - 2 * ws);
        ws1[ws] = slice2b(w1, 6 - 2 * ws);
    }
#pragma unroll
    for (int is = 0; is < 4; is++) {
        int ish = 6 - 2 * is;
        i32x4 a0 = slice2b(x0, ish), a1 = slice2b(x1, ish);
#pragma unroll
        for (int ws = 0; ws < 4; ws++) {
            i32x4 d = __builtin_amdgcn_mfma_i32_16x16x64_i8(ws0[ws], a0, zero, 0, 0, 0);
            d = __builtin_amdgcn_mfma_i32_16x16x64_i8(ws1[ws], a1, d, 0, 0, 0);
            int sh = ish + 6 - 2 * ws;
#pragma unroll
            for (int r = 0; r < 4; r++) {
                int z = d[r];
                z = z > 1024 ? 1024 : z;                 // ADC clip (z >= 0)
                int t = (z >> 2) & 1;
                int r4 = (z + 1 + t) & ~3;               // round-half-even, mult of 4
                acc4[ws][r] += r4 << sh;                 // 2^(ish+wsh)
            }
        }
    }
}

__global__ __launch_bounds__(256) void k_d(
    const unsigned char* __restrict__ Xq, const unsigned char* __restrict__ Wq,
    const float* __restrict__ xscg, const float* __restrict__ xofg,
    const float* __restrict__ xsmg,
    const float* __restrict__ wscg, const float* __restrict__ wofg,
    const float* __restrict__ wsmg, float* __restrict__ out)
{
    __shared__ __align__(16) int pacc[2][64][4];

    int tid = threadIdx.x, wv = tid >> 6, lane = tid & 63;
    int g = lane >> 4, i16 = lane & 15;
    int blk = blockIdx.x;                 // 0..1567
    int ct = blk & 7, rp = blk >> 3;      // rp 0..195
    int tl = wv & 1, khalf = wv >> 1;
    int rtile = rp * 2 + tl;              // 0..391
    const unsigned char* xt = Xq + (size_t)rtile * 10240;
    const unsigned char* wt = Wq + (size_t)ct * 10240;

    i32x4 acc4[4] = {{0,0,0,0},{0,0,0,0},{0,0,0,0},{0,0,0,0}};
    if (khalf == 0) {
        chunk_ws(xt, wt, 0, lane, acc4);
        chunk_ws(xt, wt, 1, lane, acc4);
        chunk_ws(xt, wt, 2, lane, acc4);
    } else {
        chunk_ws(xt, wt, 3, lane, acc4);
        chunk_ws(xt, wt, 4, lane, acc4);
    }
    i32x4 acc;
#pragma unroll
    for (int r = 0; r < 4; r++)
        acc[r] = (acc4[0][r] + acc4[1][r]) + (acc4[2][r] + acc4[3][r]);  // exact

    if (khalf == 0) *(i32x4*)&pacc[tl][lane][0] = acc;
    __syncthreads();

    if (khalf == 1) {
        i32x4 p = *(const i32x4*)&pacc[tl][lane][0];
#pragma unroll
        for (int r = 0; r < 4; r++) acc[r] += p[r];      // chunk-sum, exact

        // epilogue: D[row = w-row (g*4+r), col = x-row (i16)]; 64B coalesced
        int b = rtile >= 196 ? 1 : 0;
        int xrow = rtile * 16 + i16;
        float xs_ = xscg[xrow], xo = xofg[xrow], xsv = xsmg[xrow];
        int hw = (rtile - 196 * b) * 16 + i16;
#pragma unroll
        for (int r = 0; r < 4; r++) {
            int wrow = ct * 16 + g * 4 + r;
            float tt = ((float)acc[r] * xs_) * wscg[wrow];
            float res = ((tt + xo * wsmg[wrow]) + wofg[wrow] * xsv)
                      - (xo * wofg[wrow]) * 576.0f;
            out[(size_t)(b * 128 + wrow) * 3136 + hw] = res;
        }
    }
}

extern "C" void kernel_launch(void* const* d_in, const int* in_sizes, int n_in,
                              void* d_out, int out_size, void* d_ws, size_t ws_size,
                              hipStream_t stream) {
    const float* x = (const float*)d_in[0];   // [2][64][56][56]
    const float* w = (const float*)d_in[1];   // [128][64][3][3]
    float* out = (float*)d_out;               // [2][128][56][56]

    unsigned char* Xq = (unsigned char*)d_ws;          // 392*10,240 = 4,014,080 B
    unsigned char* Wq = Xq + (size_t)392 * 10240;      // 8*10,240   = 81,920 B
    float* xsc = (float*)(Wq + 8 * 10240);
    float* xof = xsc + NXROW;
    float* xsm = xof + NXROW;
    float* wsc = xsm + NXROW;
    float* wof = wsc + 128;
    float* wsm = wof + 128;

    hipLaunchKernelGGL(k_q, dim3(1600), dim3(256), 0, stream,
                       x, w, Xq, Wq, xsc, xof, xsm, wsc, wof, wsm);
    hipLaunchKernelGGL(k_d, dim3(1568), dim3(256), 0, stream,
                       Xq, Wq, xsc, xof, xsm, wsc, wof, wsm, out);
}